// Round 4
// baseline (3623.397 us; speedup 1.0000x reference)
//
#include <hip/hip_runtime.h>
#include <cstdint>

// HistogramLoss via empirical-CDF tables + exact tail handling.
// matched[i] = sorted(target)[count(input <= input[i]) - 1], loss = mean((matched-input)^2)

#define NBINS   (1u << 22)          // uniform bins over [-16, 16)
#define BINSCALE 131072.0           // NBINS / 32
#define EPB     4096u
#define NPART   (NBINS / EPB)       // 1024
#define KIN     2048u               // input tail rank cutoff (per side)
#define KTG     4096u               // target tail rank cutoff (per side)

__device__ __forceinline__ void bin_and_frac(float x, unsigned& b, double& frac) {
    double d = ((double)x + 16.0) * BINSCALE;
    if (d < 0.0) d = 0.0;
    if (d >= (double)NBINS) d = (double)NBINS - 1e-7;
    b = (unsigned)d;
    frac = d - (double)b;
}

__global__ void hist_kernel(const float* __restrict__ x, unsigned* __restrict__ H, unsigned n4) {
    unsigned i = blockIdx.x * blockDim.x + threadIdx.x;
    if (i >= n4) return;
    float4 v = ((const float4*)x)[i];
    unsigned b; double f;
    bin_and_frac(v.x, b, f); atomicAdd(&H[b], 1u);
    bin_and_frac(v.y, b, f); atomicAdd(&H[b], 1u);
    bin_and_frac(v.z, b, f); atomicAdd(&H[b], 1u);
    bin_and_frac(v.w, b, f); atomicAdd(&H[b], 1u);
}

__global__ void scanA(const unsigned* __restrict__ H, unsigned* __restrict__ partial) {
    __shared__ unsigned s[256];
    unsigned base = blockIdx.x * EPB;
    unsigned sum = 0;
    for (unsigned k = threadIdx.x; k < EPB; k += 256) sum += H[base + k];
    s[threadIdx.x] = sum; __syncthreads();
    for (int off = 128; off > 0; off >>= 1) {
        if ((int)threadIdx.x < off) s[threadIdx.x] += s[threadIdx.x + off];
        __syncthreads();
    }
    if (threadIdx.x == 0) partial[blockIdx.x] = s[0];
}

__global__ void scanB(unsigned* __restrict__ partial) {
    __shared__ unsigned s[NPART];
    unsigned v = partial[threadIdx.x];
    s[threadIdx.x] = v; __syncthreads();
    for (unsigned off = 1; off < NPART; off <<= 1) {
        unsigned t = (threadIdx.x >= off) ? s[threadIdx.x - off] : 0u;
        __syncthreads();
        s[threadIdx.x] += t;
        __syncthreads();
    }
    partial[threadIdx.x] = s[threadIdx.x] - v;  // exclusive
}

__global__ void scanC(unsigned* __restrict__ H, const unsigned* __restrict__ partial, unsigned n_total) {
    __shared__ unsigned ts[256];
    unsigned base = blockIdx.x * EPB + threadIdx.x * 16u;
    unsigned v[16]; unsigned own = 0;
    #pragma unroll
    for (int k = 0; k < 16; k++) { v[k] = H[base + k]; own += v[k]; }
    ts[threadIdx.x] = own; __syncthreads();
    for (unsigned off = 1; off < 256; off <<= 1) {
        unsigned t = (threadIdx.x >= off) ? ts[threadIdx.x - off] : 0u;
        __syncthreads();
        ts[threadIdx.x] += t;
        __syncthreads();
    }
    unsigned ex = ts[threadIdx.x] - own + partial[blockIdx.x];
    #pragma unroll
    for (int k = 0; k < 16; k++) { unsigned t = v[k]; H[base + k] = ex; ex += t; }
    if (blockIdx.x == gridDim.x - 1 && threadIdx.x == 255) H[NBINS] = n_total;
}

__global__ void buildT(const unsigned* __restrict__ Ctg, float* __restrict__ T) {
    unsigned b = blockIdx.x * blockDim.x + threadIdx.x;
    if (b >= NBINS) return;
    unsigned c0 = Ctg[b], c1 = Ctg[b + 1];
    unsigned cnt = c1 - c0;
    if (cnt == 0) return;
    float lo = (float)(-16.0 + (double)b * (32.0 / (double)NBINS));
    float w  = (float)(32.0 / (double)NBINS);
    float inv = 1.0f / (float)cnt;
    for (unsigned k = 0; k < cnt; k++)
        T[c0 + k] = lo + w * ((float)(k + 1) * inv);
}

// Collect tail elements. Whole-bin criterion: bottom if C[b+1] <= K, top if C[b] >= n-K.
__global__ void collect_kernel(const float* __restrict__ x, const unsigned* __restrict__ C,
                               float* __restrict__ vlo, unsigned* __restrict__ ilo,
                               float* __restrict__ vhi, unsigned* __restrict__ ihi,
                               unsigned* __restrict__ ctr_lo, unsigned* __restrict__ ctr_hi,
                               unsigned n, unsigned K, unsigned cap, int want_idx) {
    unsigned i = blockIdx.x * blockDim.x + threadIdx.x;
    if (i >= n) return;
    float v = x[i];
    unsigned b; double f;
    bin_and_frac(v, b, f);
    unsigned c0 = C[b], c1 = C[b + 1];
    if (c1 <= K) {
        unsigned p = atomicAdd(ctr_lo, 1u);
        if (p < cap) { vlo[p] = v; if (want_idx) ilo[p] = i; }
    } else if (c0 >= n - K) {
        unsigned p = atomicAdd(ctr_hi, 1u);
        if (p < cap) { vhi[p] = v; if (want_idx) ihi[p] = i; }
    }
}

// Exact target order statistics: overwrite both ends of T.
// blockIdx 0 = bottom, 1 = top. 1024 threads.
__global__ void exact_target_kernel(const float* __restrict__ tg_lo, const float* __restrict__ tg_hi,
                                    const unsigned* __restrict__ ctrs, float* __restrict__ T,
                                    unsigned n) {
    __shared__ float v[KTG];
    int side = blockIdx.x;
    const float* src = side ? tg_hi : tg_lo;
    unsigned m = ctrs[side ? 3 : 2];
    if (m > KTG) m = KTG;
    for (unsigned k = threadIdx.x; k < m; k += 1024) v[k] = src[k];
    __syncthreads();
    for (unsigned j = threadIdx.x; j < m; j += 1024) {
        float y = v[j];
        unsigned lt = 0, le = 0;  // bottom: counts <, <= ; top: counts >, >=
        for (unsigned k = 0; k < m; k++) {
            float z = v[k];
            if (side) { lt += (z > y); le += (z >= y); }
            else      { lt += (z < y); le += (z <= y); }
        }
        if (side) {
            // global ranks [n-le, n-lt)
            for (unsigned r = n - le; r < n - lt; r++) T[r] = y;
        } else {
            for (unsigned r = lt; r < le; r++) T[r] = y;
        }
    }
}

// Exact input tail matching. blockIdx 0 = bottom, 1 = top. 1024 threads.
__global__ void exact_input_kernel(const float* __restrict__ in_lo_v, const unsigned* __restrict__ in_lo_i,
                                   const float* __restrict__ in_hi_v, const unsigned* __restrict__ in_hi_i,
                                   const unsigned* __restrict__ ctrs, const float* __restrict__ T,
                                   float* __restrict__ out, float* __restrict__ loss, unsigned n) {
    __shared__ float v[KIN];
    __shared__ unsigned id[KIN];
    int side = blockIdx.x;
    const float* sv = side ? in_hi_v : in_lo_v;
    const unsigned* si = side ? in_hi_i : in_lo_i;
    unsigned m = ctrs[side ? 1 : 0];
    if (m > KIN) m = KIN;
    for (unsigned k = threadIdx.x; k < m; k += 1024) { v[k] = sv[k]; id[k] = si[k]; }
    __syncthreads();
    float inv_n = 1.0f / (float)n;
    for (unsigned j = threadIdx.x; j < m; j += 1024) {
        float x = v[j];
        unsigned cnt = 0;
        long long r;
        if (side) {
            for (unsigned k = 0; k < m; k++) cnt += (v[k] > x);
            r = (long long)n - 1 - (long long)cnt;           // count(<=x)-1 globally
        } else {
            for (unsigned k = 0; k < m; k++) cnt += (v[k] <= x);
            r = (long long)cnt - 1;
        }
        if (r < 0) r = 0;
        if (r > (long long)n - 1) r = (long long)n - 1;
        float mv = T[r];
        out[id[j]] = mv;
        float d = mv - x;
        atomicAdd(loss, d * d * inv_n);
    }
}

__global__ void match_loss_kernel(const float* __restrict__ input,
                                  const unsigned* __restrict__ Cin,
                                  const float* __restrict__ T,
                                  float* __restrict__ out, float* __restrict__ loss,
                                  unsigned n) {
    unsigned i = blockIdx.x * blockDim.x + threadIdx.x;
    unsigned n4 = n >> 2;
    float acc = 0.f;
    if (i < n4) {
        float4 vv = ((const float4*)input)[i];
        float xs[4] = {vv.x, vv.y, vv.z, vv.w};
        float m[4]; bool tail[4]; bool anytail = false;
        #pragma unroll
        for (int k = 0; k < 4; k++) {
            float x = xs[k];
            unsigned b; double frac;
            bin_and_frac(x, b, frac);
            unsigned c0 = Cin[b], c1 = Cin[b + 1];
            tail[k] = (c1 <= KIN) || (c0 >= n - KIN);
            if (tail[k]) { anytail = true; m[k] = 0.f; continue; }
            unsigned cnt = c1 - c0;
            long long j = (long long)((double)c0 + frac * (double)cnt);
            long long jmax = (long long)c1 - 1;
            if (j > jmax) j = jmax;
            if (j < (long long)c0) j = (long long)c0;
            if (j > (long long)n - 1) j = (long long)n - 1;
            float mv = T[j];
            m[k] = mv;
            float d = mv - x;
            acc += d * d;
        }
        if (!anytail) {
            ((float4*)out)[i] = make_float4(m[0], m[1], m[2], m[3]);
        } else {
            #pragma unroll
            for (int k = 0; k < 4; k++)
                if (!tail[k]) out[4 * i + k] = m[k];
        }
    }
    #pragma unroll
    for (int off = 32; off > 0; off >>= 1) acc += __shfl_down(acc, off, 64);
    __shared__ float wsum[4];
    int wv = threadIdx.x >> 6;
    if ((threadIdx.x & 63) == 0) wsum[wv] = acc;
    __syncthreads();
    if (threadIdx.x == 0)
        atomicAdd(loss, (wsum[0] + wsum[1] + wsum[2] + wsum[3]) * (1.0f / (float)n));
}

extern "C" void kernel_launch(void* const* d_in, const int* in_sizes, int n_in,
                              void* d_out, int out_size, void* d_ws, size_t ws_size,
                              hipStream_t stream) {
    const float* input  = (const float*)d_in[0];
    const float* target = (const float*)d_in[1];
    unsigned n = (unsigned)in_sizes[0];   // 16777216 = 2^24
    float* out  = (float*)d_out;
    float* loss = out + n;

    char* wsb = (char*)d_ws;
    size_t cdf_sz = (size_t)(NBINS + 64) * 4;
    unsigned* Cin     = (unsigned*)(wsb);
    unsigned* Ctg     = (unsigned*)(wsb + cdf_sz);
    unsigned* partial = (unsigned*)(wsb + 2 * cdf_sz);
    float*    T       = (float*)   (wsb + 2 * cdf_sz + 8192);
    char*     tails   = wsb + 2 * cdf_sz + 8192 + (size_t)n * 4;
    unsigned* ctrs    = (unsigned*)(tails);               // [in_lo, in_hi, tg_lo, tg_hi]
    float*    in_lo_v = (float*)   (tails + 256);
    unsigned* in_lo_i = (unsigned*)(tails + 256 + KIN * 4);
    float*    in_hi_v = (float*)   (tails + 256 + KIN * 8);
    unsigned* in_hi_i = (unsigned*)(tails + 256 + KIN * 12);
    float*    tg_lo   = (float*)   (tails + 256 + KIN * 16);
    float*    tg_hi   = (float*)   (tails + 256 + KIN * 16 + KTG * 4);

    (void)hipMemsetAsync(Cin, 0, (size_t)(NBINS + 1) * 4, stream);
    (void)hipMemsetAsync(Ctg, 0, (size_t)(NBINS + 1) * 4, stream);
    (void)hipMemsetAsync(loss, 0, 4, stream);
    (void)hipMemsetAsync(ctrs, 0, 16, stream);

    unsigned n4 = n >> 2;
    unsigned gh = (n4 + 255) / 256;
    unsigned gn = (n + 255) / 256;

    hist_kernel<<<gh, 256, 0, stream>>>(input,  Cin, n4);
    hist_kernel<<<gh, 256, 0, stream>>>(target, Ctg, n4);

    scanA<<<NPART, 256, 0, stream>>>(Cin, partial);
    scanB<<<1, NPART, 0, stream>>>(partial);
    scanC<<<NPART, 256, 0, stream>>>(Cin, partial, n);

    scanA<<<NPART, 256, 0, stream>>>(Ctg, partial);
    scanB<<<1, NPART, 0, stream>>>(partial);
    scanC<<<NPART, 256, 0, stream>>>(Ctg, partial, n);

    buildT<<<(NBINS + 255) / 256, 256, 0, stream>>>(Ctg, T);

    // tails: collect, then exact target order stats (overwrite T ends), then exact input match
    collect_kernel<<<gn, 256, 0, stream>>>(input, Cin, in_lo_v, in_lo_i, in_hi_v, in_hi_i,
                                           &ctrs[0], &ctrs[1], n, KIN, KIN, 1);
    collect_kernel<<<gn, 256, 0, stream>>>(target, Ctg, tg_lo, nullptr, tg_hi, nullptr,
                                           &ctrs[2], &ctrs[3], n, KTG, KTG, 0);
    exact_target_kernel<<<2, 1024, 0, stream>>>(tg_lo, tg_hi, ctrs, T, n);
    exact_input_kernel<<<2, 1024, 0, stream>>>(in_lo_v, in_lo_i, in_hi_v, in_hi_i, ctrs, T,
                                               out, loss, n);

    match_loss_kernel<<<gh, 256, 0, stream>>>(input, Cin, T, out, loss, n);
}

// Round 5
// 2328.138 us; speedup vs baseline: 1.5563x; 1.5563x over previous
//
#include <hip/hip_runtime.h>
#include <cstdint>

// HistogramLoss via empirical-CDF tables + exact tail handling.
// matched[i] = sorted(target)[count(input <= input[i]) - 1], loss = mean((matched-input)^2)

#define NBINS   (1u << 22)          // uniform bins over [-16, 16)
#define BINSCALE 131072.0           // NBINS / 32
#define EPB     4096u
#define NPART   (NBINS / EPB)       // 1024
#define KIN     2048u               // input tail rank cutoff (per side)
#define KTG     4096u               // target tail rank cutoff (per side)

__device__ __forceinline__ void bin_and_frac(float x, unsigned& b, double& frac) {
    double d = ((double)x + 16.0) * BINSCALE;
    if (d < 0.0) d = 0.0;
    if (d >= (double)NBINS) d = (double)NBINS - 1e-7;
    b = (unsigned)d;
    frac = d - (double)b;
}

__global__ void hist_kernel(const float* __restrict__ x, unsigned* __restrict__ H, unsigned n4) {
    unsigned i = blockIdx.x * blockDim.x + threadIdx.x;
    if (i >= n4) return;
    float4 v = ((const float4*)x)[i];
    unsigned b; double f;
    bin_and_frac(v.x, b, f); atomicAdd(&H[b], 1u);
    bin_and_frac(v.y, b, f); atomicAdd(&H[b], 1u);
    bin_and_frac(v.z, b, f); atomicAdd(&H[b], 1u);
    bin_and_frac(v.w, b, f); atomicAdd(&H[b], 1u);
}

__global__ void scanA(const unsigned* __restrict__ H, unsigned* __restrict__ partial) {
    __shared__ unsigned s[256];
    unsigned base = blockIdx.x * EPB;
    unsigned sum = 0;
    for (unsigned k = threadIdx.x; k < EPB; k += 256) sum += H[base + k];
    s[threadIdx.x] = sum; __syncthreads();
    for (int off = 128; off > 0; off >>= 1) {
        if ((int)threadIdx.x < off) s[threadIdx.x] += s[threadIdx.x + off];
        __syncthreads();
    }
    if (threadIdx.x == 0) partial[blockIdx.x] = s[0];
}

__global__ void scanB(unsigned* __restrict__ partial) {
    __shared__ unsigned s[NPART];
    unsigned v = partial[threadIdx.x];
    s[threadIdx.x] = v; __syncthreads();
    for (unsigned off = 1; off < NPART; off <<= 1) {
        unsigned t = (threadIdx.x >= off) ? s[threadIdx.x - off] : 0u;
        __syncthreads();
        s[threadIdx.x] += t;
        __syncthreads();
    }
    partial[threadIdx.x] = s[threadIdx.x] - v;  // exclusive
}

__global__ void scanC(unsigned* __restrict__ H, const unsigned* __restrict__ partial, unsigned n_total) {
    __shared__ unsigned ts[256];
    unsigned base = blockIdx.x * EPB + threadIdx.x * 16u;
    unsigned v[16]; unsigned own = 0;
    #pragma unroll
    for (int k = 0; k < 16; k++) { v[k] = H[base + k]; own += v[k]; }
    ts[threadIdx.x] = own; __syncthreads();
    for (unsigned off = 1; off < 256; off <<= 1) {
        unsigned t = (threadIdx.x >= off) ? ts[threadIdx.x - off] : 0u;
        __syncthreads();
        ts[threadIdx.x] += t;
        __syncthreads();
    }
    unsigned ex = ts[threadIdx.x] - own + partial[blockIdx.x];
    #pragma unroll
    for (int k = 0; k < 16; k++) { unsigned t = v[k]; H[base + k] = ex; ex += t; }
    if (blockIdx.x == gridDim.x - 1 && threadIdx.x == 255) H[NBINS] = n_total;
}

__global__ void buildT(const unsigned* __restrict__ Ctg, float* __restrict__ T) {
    unsigned b = blockIdx.x * blockDim.x + threadIdx.x;
    if (b >= NBINS) return;
    unsigned c0 = Ctg[b], c1 = Ctg[b + 1];
    unsigned cnt = c1 - c0;
    if (cnt == 0) return;
    float lo = (float)(-16.0 + (double)b * (32.0 / (double)NBINS));
    float w  = (float)(32.0 / (double)NBINS);
    float inv = 1.0f / (float)cnt;
    for (unsigned k = 0; k < cnt; k++)
        T[c0 + k] = lo + w * ((float)(k + 1) * inv);
}

// Collect tail elements. Whole-bin criterion: bottom if C[b+1] <= K, top if C[b] >= n-K.
// Collected sets are rank-downward/upward closed, so counts never exceed K.
__global__ void collect_kernel(const float* __restrict__ x, const unsigned* __restrict__ C,
                               float* __restrict__ vlo, unsigned* __restrict__ ilo,
                               float* __restrict__ vhi, unsigned* __restrict__ ihi,
                               unsigned* __restrict__ ctr_lo, unsigned* __restrict__ ctr_hi,
                               unsigned n, unsigned K, int want_idx) {
    unsigned i = blockIdx.x * blockDim.x + threadIdx.x;
    if (i >= n) return;
    float v = x[i];
    unsigned b; double f;
    bin_and_frac(v, b, f);
    unsigned c0 = C[b], c1 = C[b + 1];
    if (c1 <= K) {
        unsigned p = atomicAdd(ctr_lo, 1u);
        vlo[p] = v; if (want_idx) ilo[p] = i;
    } else if (c0 >= n - K) {
        unsigned p = atomicAdd(ctr_hi, 1u);
        vhi[p] = v; if (want_idx) ihi[p] = i;
    }
}

// Exact target order statistics: overwrite both ends of T with exact values.
// grid (4, 2): blockIdx.y = side (0 bottom, 1 top), 1024 threads, one j per thread.
__global__ void exact_target_kernel(const float* __restrict__ tg_lo, const float* __restrict__ tg_hi,
                                    const unsigned* __restrict__ ctrs, float* __restrict__ T,
                                    unsigned n) {
    __shared__ __align__(16) float v[KTG];
    int side = blockIdx.y;
    const float* src = side ? tg_hi : tg_lo;
    unsigned m = ctrs[side ? 3 : 2];
    if (m > KTG) m = KTG;
    float sgn = side ? -1.f : 1.f;
    for (unsigned k = threadIdx.x; k < m; k += 1024) v[k] = sgn * src[k];
    __syncthreads();
    unsigned j = blockIdx.x * 1024 + threadIdx.x;
    if (j >= m) return;
    float y = v[j];
    unsigned lt = 0, le = 0;
    unsigned m4 = m & ~3u;
    for (unsigned k = 0; k < m4; k += 4) {
        float4 z = *(const float4*)&v[k];
        lt += (z.x < y) + (z.y < y) + (z.z < y) + (z.w < y);
        le += (z.x <= y) + (z.y <= y) + (z.z <= y) + (z.w <= y);
    }
    for (unsigned k = m4; k < m; k++) { lt += (v[k] < y); le += (v[k] <= y); }
    float yo = sgn * y;
    if (side) {
        for (unsigned r = n - le; r < n - lt; r++) T[r] = yo;  // ranks of tied group
    } else {
        for (unsigned r = lt; r < le; r++) T[r] = yo;
    }
}

// Exact input tail matching. grid (2, 2): blockIdx.y = side, one j per thread.
__global__ void exact_input_kernel(const float* __restrict__ in_lo_v, const unsigned* __restrict__ in_lo_i,
                                   const float* __restrict__ in_hi_v, const unsigned* __restrict__ in_hi_i,
                                   const unsigned* __restrict__ ctrs, const float* __restrict__ T,
                                   float* __restrict__ out, float* __restrict__ loss, unsigned n) {
    __shared__ __align__(16) float v[KIN];
    int side = blockIdx.y;
    const float* sv = side ? in_hi_v : in_lo_v;
    const unsigned* si = side ? in_hi_i : in_lo_i;
    unsigned m = ctrs[side ? 1 : 0];
    if (m > KIN) m = KIN;
    float sgn = side ? -1.f : 1.f;
    for (unsigned k = threadIdx.x; k < m; k += 1024) v[k] = sgn * sv[k];
    __syncthreads();
    unsigned j = blockIdx.x * 1024 + threadIdx.x;
    float d2 = 0.f;
    if (j < m) {
        float y = v[j];
        unsigned lt = 0, le = 0;
        unsigned m4 = m & ~3u;
        for (unsigned k = 0; k < m4; k += 4) {
            float4 z = *(const float4*)&v[k];
            lt += (z.x < y) + (z.y < y) + (z.z < y) + (z.w < y);
            le += (z.x <= y) + (z.y <= y) + (z.z <= y) + (z.w <= y);
        }
        for (unsigned k = m4; k < m; k++) { lt += (v[k] < y); le += (v[k] <= y); }
        // bottom: global rank = count(<= x) - 1 = le - 1 (collected set is downward closed)
        // top:    count(> x) = lt (in negated space), rank = n - 1 - lt
        long long r = side ? ((long long)n - 1 - (long long)lt) : ((long long)le - 1);
        if (r < 0) r = 0;
        if (r > (long long)n - 1) r = (long long)n - 1;
        float mv = T[r];
        float x = sgn * y;
        out[si[j]] = mv;
        float d = mv - x;
        d2 = d * d;
    }
    #pragma unroll
    for (int off = 32; off > 0; off >>= 1) d2 += __shfl_down(d2, off, 64);
    if ((threadIdx.x & 63) == 0 && d2 != 0.f)
        atomicAdd(loss, d2 * (1.0f / (float)n));
}

__global__ void match_loss_kernel(const float* __restrict__ input,
                                  const unsigned* __restrict__ Cin,
                                  const float* __restrict__ T,
                                  float* __restrict__ out, float* __restrict__ loss,
                                  unsigned n) {
    unsigned i = blockIdx.x * blockDim.x + threadIdx.x;
    unsigned n4 = n >> 2;
    float acc = 0.f;
    if (i < n4) {
        float4 vv = ((const float4*)input)[i];
        float xs[4] = {vv.x, vv.y, vv.z, vv.w};
        float m[4]; bool tail[4]; bool anytail = false;
        #pragma unroll
        for (int k = 0; k < 4; k++) {
            float x = xs[k];
            unsigned b; double frac;
            bin_and_frac(x, b, frac);
            unsigned c0 = Cin[b], c1 = Cin[b + 1];
            tail[k] = (c1 <= KIN) || (c0 >= n - KIN);
            if (tail[k]) { anytail = true; m[k] = 0.f; continue; }
            unsigned cnt = c1 - c0;
            long long j = (long long)((double)c0 + frac * (double)cnt);
            long long jmax = (long long)c1 - 1;
            if (j > jmax) j = jmax;
            if (j < (long long)c0) j = (long long)c0;
            if (j > (long long)n - 1) j = (long long)n - 1;
            float mv = T[j];
            m[k] = mv;
            float d = mv - x;
            acc += d * d;
        }
        if (!anytail) {
            ((float4*)out)[i] = make_float4(m[0], m[1], m[2], m[3]);
        } else {
            #pragma unroll
            for (int k = 0; k < 4; k++)
                if (!tail[k]) out[4 * i + k] = m[k];
        }
    }
    #pragma unroll
    for (int off = 32; off > 0; off >>= 1) acc += __shfl_down(acc, off, 64);
    __shared__ float wsum[4];
    int wv = threadIdx.x >> 6;
    if ((threadIdx.x & 63) == 0) wsum[wv] = acc;
    __syncthreads();
    if (threadIdx.x == 0)
        atomicAdd(loss, (wsum[0] + wsum[1] + wsum[2] + wsum[3]) * (1.0f / (float)n));
}

extern "C" void kernel_launch(void* const* d_in, const int* in_sizes, int n_in,
                              void* d_out, int out_size, void* d_ws, size_t ws_size,
                              hipStream_t stream) {
    const float* input  = (const float*)d_in[0];
    const float* target = (const float*)d_in[1];
    unsigned n = (unsigned)in_sizes[0];   // 16777216 = 2^24
    float* out  = (float*)d_out;
    float* loss = out + n;

    char* wsb = (char*)d_ws;
    size_t cdf_sz = (size_t)(NBINS + 64) * 4;
    unsigned* Cin     = (unsigned*)(wsb);
    unsigned* Ctg     = (unsigned*)(wsb + cdf_sz);
    unsigned* partial = (unsigned*)(wsb + 2 * cdf_sz);
    float*    T       = (float*)   (wsb + 2 * cdf_sz + 8192);
    char*     tails   = wsb + 2 * cdf_sz + 8192 + (size_t)n * 4;
    unsigned* ctrs    = (unsigned*)(tails);               // [in_lo, in_hi, tg_lo, tg_hi]
    float*    in_lo_v = (float*)   (tails + 256);
    unsigned* in_lo_i = (unsigned*)(tails + 256 + KIN * 4);
    float*    in_hi_v = (float*)   (tails + 256 + KIN * 8);
    unsigned* in_hi_i = (unsigned*)(tails + 256 + KIN * 12);
    float*    tg_lo   = (float*)   (tails + 256 + KIN * 16);
    float*    tg_hi   = (float*)   (tails + 256 + KIN * 16 + KTG * 4);

    (void)hipMemsetAsync(Cin, 0, (size_t)(NBINS + 1) * 4, stream);
    (void)hipMemsetAsync(Ctg, 0, (size_t)(NBINS + 1) * 4, stream);
    (void)hipMemsetAsync(loss, 0, 4, stream);
    (void)hipMemsetAsync(ctrs, 0, 16, stream);

    unsigned n4 = n >> 2;
    unsigned gh = (n4 + 255) / 256;
    unsigned gn = (n + 255) / 256;

    hist_kernel<<<gh, 256, 0, stream>>>(input,  Cin, n4);
    hist_kernel<<<gh, 256, 0, stream>>>(target, Ctg, n4);

    scanA<<<NPART, 256, 0, stream>>>(Cin, partial);
    scanB<<<1, NPART, 0, stream>>>(partial);
    scanC<<<NPART, 256, 0, stream>>>(Cin, partial, n);

    scanA<<<NPART, 256, 0, stream>>>(Ctg, partial);
    scanB<<<1, NPART, 0, stream>>>(partial);
    scanC<<<NPART, 256, 0, stream>>>(Ctg, partial, n);

    buildT<<<(NBINS + 255) / 256, 256, 0, stream>>>(Ctg, T);

    // tails: collect, then exact target order stats (overwrite T ends), then exact input match
    collect_kernel<<<gn, 256, 0, stream>>>(input, Cin, in_lo_v, in_lo_i, in_hi_v, in_hi_i,
                                           &ctrs[0], &ctrs[1], n, KIN, 1);
    collect_kernel<<<gn, 256, 0, stream>>>(target, Ctg, tg_lo, nullptr, tg_hi, nullptr,
                                           &ctrs[2], &ctrs[3], n, KTG, 0);
    exact_target_kernel<<<dim3((KTG + 1023) / 1024, 2), 1024, 0, stream>>>(tg_lo, tg_hi, ctrs, T, n);
    exact_input_kernel<<<dim3((KIN + 1023) / 1024, 2), 1024, 0, stream>>>(in_lo_v, in_lo_i, in_hi_v, in_hi_i,
                                                                          ctrs, T, out, loss, n);

    match_loss_kernel<<<gh, 256, 0, stream>>>(input, Cin, T, out, loss, n);
}

// Round 6
// 885.346 us; speedup vs baseline: 4.0926x; 2.6296x over previous
//
#include <hip/hip_runtime.h>
#include <cstdint>

// HistogramLoss via coarse empirical-CDF tables (LDS histograms) + exact tail handling.
// matched[i] = sorted(target)[count(input <= input[i]) - 1], loss = mean((matched-input)^2)

#define NBINS    8192u              // uniform bins over [-16, 16), 32 KB LDS histogram
#define BINSCALE 256.0              // NBINS / 32
#define HBLOCKS  512u               // histogram partial blocks
#define KIN      2048u              // input tail rank cutoff (per side)
#define KTG      4096u              // target tail rank cutoff (per side)

__device__ __forceinline__ void bin_and_frac(float x, unsigned& b, double& frac) {
    double d = ((double)x + 16.0) * BINSCALE;
    if (d < 0.0) d = 0.0;
    if (d >= (double)NBINS) d = (double)NBINS - 1e-7;
    b = (unsigned)d;
    frac = d - (double)b;
}

// LDS-private histogram; flush per-block partials with plain coalesced stores (no global atomics).
__global__ void hist_kernel(const float* __restrict__ x, unsigned* __restrict__ partials, unsigned n4) {
    __shared__ unsigned h[NBINS];
    for (unsigned i = threadIdx.x; i < NBINS; i += 256) h[i] = 0;
    __syncthreads();
    unsigned stride = gridDim.x * 256;
    for (unsigned i = blockIdx.x * 256 + threadIdx.x; i < n4; i += stride) {
        float4 v = ((const float4*)x)[i];
        unsigned b; double f;
        bin_and_frac(v.x, b, f); atomicAdd(&h[b], 1u);
        bin_and_frac(v.y, b, f); atomicAdd(&h[b], 1u);
        bin_and_frac(v.z, b, f); atomicAdd(&h[b], 1u);
        bin_and_frac(v.w, b, f); atomicAdd(&h[b], 1u);
    }
    __syncthreads();
    unsigned base = blockIdx.x * NBINS;
    for (unsigned i = threadIdx.x; i < NBINS; i += 256) partials[base + i] = h[i];
}

// Column-sum of HBLOCKS x NBINS partial matrices (2 histograms back to back). No atomics.
__global__ void reduce_kernel(const unsigned* __restrict__ partials, unsigned* __restrict__ H) {
    unsigned col = blockIdx.x * 256 + threadIdx.x;           // [0, 2*NBINS)
    unsigned hist = col / NBINS, c = col & (NBINS - 1);
    const unsigned* p = partials + (size_t)hist * HBLOCKS * NBINS + c;
    unsigned s0 = 0, s1 = 0, s2 = 0, s3 = 0;
    for (unsigned k = 0; k < HBLOCKS; k += 4) {
        s0 += p[(size_t)k * NBINS];
        s1 += p[(size_t)(k + 1) * NBINS];
        s2 += p[(size_t)(k + 2) * NBINS];
        s3 += p[(size_t)(k + 3) * NBINS];
    }
    H[col] = s0 + s1 + s2 + s3;
}

// Exclusive scan of one 8192-bin histogram per block -> C[NBINS+1]. grid = 2 blocks.
__global__ void scan_kernel(const unsigned* __restrict__ H, unsigned* __restrict__ C) {
    __shared__ unsigned s[1024];
    const unsigned* h = H + blockIdx.x * NBINS;
    unsigned* c = C + blockIdx.x * (NBINS + 1);
    unsigned base = threadIdx.x * 8;
    unsigned v[8]; unsigned own = 0;
    #pragma unroll
    for (int k = 0; k < 8; k++) { v[k] = h[base + k]; own += v[k]; }
    s[threadIdx.x] = own; __syncthreads();
    for (unsigned off = 1; off < 1024; off <<= 1) {
        unsigned t = (threadIdx.x >= off) ? s[threadIdx.x - off] : 0u;
        __syncthreads();
        s[threadIdx.x] += t;
        __syncthreads();
    }
    unsigned ex = s[threadIdx.x] - own;
    #pragma unroll
    for (int k = 0; k < 8; k++) { unsigned t = v[k]; c[base + k] = ex; ex += t; }
    if (threadIdx.x == 1023) c[NBINS] = s[1023];
}

// T[r] = interpolated r-th order statistic of target. Thread handles 4 consecutive ranks.
__global__ void buildT_kernel(const unsigned* __restrict__ Ctg, float* __restrict__ T, unsigned n) {
    unsigned j = blockIdx.x * blockDim.x + threadIdx.x;
    if (j >= (n >> 2)) return;
    unsigned r0 = j * 4;
    unsigned lo = 0, hi = NBINS;
    while (hi - lo > 1) {                 // invariant: Ctg[lo] <= r0 < Ctg[hi]
        unsigned mid = (lo + hi) >> 1;
        if (Ctg[mid] <= r0) lo = mid; else hi = mid;
    }
    const float w = 32.0f / (float)NBINS;
    float out[4];
    #pragma unroll
    for (int k = 0; k < 4; k++) {
        unsigned r = r0 + k;
        while (Ctg[lo + 1] <= r) lo++;    // walk to containing (non-empty) bin
        unsigned c0 = Ctg[lo], c1 = Ctg[lo + 1];
        float binlo = -16.0f + (float)lo * w;
        out[k] = binlo + w * ((float)(r - c0 + 1) / (float)(c1 - c0));
    }
    ((float4*)T)[j] = make_float4(out[0], out[1], out[2], out[3]);
}

// Collect tail elements. Whole-bin criterion: bottom if C[b+1] <= K, top if C[b] >= n-K.
// Collected sets are rank-downward/upward closed, so counts never exceed K.
__global__ void collect_kernel(const float* __restrict__ x, const unsigned* __restrict__ C,
                               float* __restrict__ vlo, unsigned* __restrict__ ilo,
                               float* __restrict__ vhi, unsigned* __restrict__ ihi,
                               unsigned* __restrict__ ctr_lo, unsigned* __restrict__ ctr_hi,
                               unsigned n, unsigned K, int want_idx) {
    unsigned i = blockIdx.x * blockDim.x + threadIdx.x;
    if (i >= n) return;
    float v = x[i];
    unsigned b; double f;
    bin_and_frac(v, b, f);
    unsigned c0 = C[b], c1 = C[b + 1];
    if (c1 <= K) {
        unsigned p = atomicAdd(ctr_lo, 1u);
        vlo[p] = v; if (want_idx) ilo[p] = i;
    } else if (c0 >= n - K) {
        unsigned p = atomicAdd(ctr_hi, 1u);
        vhi[p] = v; if (want_idx) ihi[p] = i;
    }
}

// Exact target order statistics: overwrite both ends of T with exact values.
// grid (4, 2): blockIdx.y = side (0 bottom, 1 top), one j per thread.
__global__ void exact_target_kernel(const float* __restrict__ tg_lo, const float* __restrict__ tg_hi,
                                    const unsigned* __restrict__ ctrs, float* __restrict__ T,
                                    unsigned n) {
    __shared__ __align__(16) float v[KTG];
    int side = blockIdx.y;
    const float* src = side ? tg_hi : tg_lo;
    unsigned m = ctrs[side ? 3 : 2];
    if (m > KTG) m = KTG;
    float sgn = side ? -1.f : 1.f;
    for (unsigned k = threadIdx.x; k < m; k += 1024) v[k] = sgn * src[k];
    __syncthreads();
    unsigned j = blockIdx.x * 1024 + threadIdx.x;
    if (j >= m) return;
    float y = v[j];
    unsigned lt = 0, le = 0;
    unsigned m4 = m & ~3u;
    for (unsigned k = 0; k < m4; k += 4) {
        float4 z = *(const float4*)&v[k];
        lt += (z.x < y) + (z.y < y) + (z.z < y) + (z.w < y);
        le += (z.x <= y) + (z.y <= y) + (z.z <= y) + (z.w <= y);
    }
    for (unsigned k = m4; k < m; k++) { lt += (v[k] < y); le += (v[k] <= y); }
    float yo = sgn * y;
    if (side) {
        for (unsigned r = n - le; r < n - lt; r++) T[r] = yo;  // ranks of tied group
    } else {
        for (unsigned r = lt; r < le; r++) T[r] = yo;
    }
}

// Exact input tail matching. grid (2, 2): blockIdx.y = side, one j per thread.
__global__ void exact_input_kernel(const float* __restrict__ in_lo_v, const unsigned* __restrict__ in_lo_i,
                                   const float* __restrict__ in_hi_v, const unsigned* __restrict__ in_hi_i,
                                   const unsigned* __restrict__ ctrs, const float* __restrict__ T,
                                   float* __restrict__ out, float* __restrict__ loss, unsigned n) {
    __shared__ __align__(16) float v[KIN];
    int side = blockIdx.y;
    const float* sv = side ? in_hi_v : in_lo_v;
    const unsigned* si = side ? in_hi_i : in_lo_i;
    unsigned m = ctrs[side ? 1 : 0];
    if (m > KIN) m = KIN;
    float sgn = side ? -1.f : 1.f;
    for (unsigned k = threadIdx.x; k < m; k += 1024) v[k] = sgn * sv[k];
    __syncthreads();
    unsigned j = blockIdx.x * 1024 + threadIdx.x;
    float d2 = 0.f;
    if (j < m) {
        float y = v[j];
        unsigned lt = 0, le = 0;
        unsigned m4 = m & ~3u;
        for (unsigned k = 0; k < m4; k += 4) {
            float4 z = *(const float4*)&v[k];
            lt += (z.x < y) + (z.y < y) + (z.z < y) + (z.w < y);
            le += (z.x <= y) + (z.y <= y) + (z.z <= y) + (z.w <= y);
        }
        for (unsigned k = m4; k < m; k++) { lt += (v[k] < y); le += (v[k] <= y); }
        long long r = side ? ((long long)n - 1 - (long long)lt) : ((long long)le - 1);
        if (r < 0) r = 0;
        if (r > (long long)n - 1) r = (long long)n - 1;
        float mv = T[r];
        float x = sgn * y;
        out[si[j]] = mv;
        float d = mv - x;
        d2 = d * d;
    }
    #pragma unroll
    for (int off = 32; off > 0; off >>= 1) d2 += __shfl_down(d2, off, 64);
    if ((threadIdx.x & 63) == 0 && d2 != 0.f)
        atomicAdd(loss, d2 * (1.0f / (float)n));
}

__global__ void match_loss_kernel(const float* __restrict__ input,
                                  const unsigned* __restrict__ Cin,
                                  const float* __restrict__ T,
                                  float* __restrict__ out, float* __restrict__ loss,
                                  unsigned n) {
    unsigned i = blockIdx.x * blockDim.x + threadIdx.x;
    unsigned n4 = n >> 2;
    float acc = 0.f;
    if (i < n4) {
        float4 vv = ((const float4*)input)[i];
        float xs[4] = {vv.x, vv.y, vv.z, vv.w};
        float m[4]; bool tail[4]; bool anytail = false;
        #pragma unroll
        for (int k = 0; k < 4; k++) {
            float x = xs[k];
            unsigned b; double frac;
            bin_and_frac(x, b, frac);
            unsigned c0 = Cin[b], c1 = Cin[b + 1];
            tail[k] = (c1 <= KIN) || (c0 >= n - KIN);
            if (tail[k]) { anytail = true; m[k] = 0.f; continue; }
            unsigned cnt = c1 - c0;
            long long j = (long long)((double)c0 + frac * (double)cnt);
            long long jmax = (long long)c1 - 1;
            if (j > jmax) j = jmax;
            if (j < (long long)c0) j = (long long)c0;
            if (j > (long long)n - 1) j = (long long)n - 1;
            float mv = T[j];
            m[k] = mv;
            float d = mv - x;
            acc += d * d;
        }
        if (!anytail) {
            ((float4*)out)[i] = make_float4(m[0], m[1], m[2], m[3]);
        } else {
            #pragma unroll
            for (int k = 0; k < 4; k++)
                if (!tail[k]) out[4 * i + k] = m[k];
        }
    }
    #pragma unroll
    for (int off = 32; off > 0; off >>= 1) acc += __shfl_down(acc, off, 64);
    __shared__ float wsum[4];
    int wv = threadIdx.x >> 6;
    if ((threadIdx.x & 63) == 0) wsum[wv] = acc;
    __syncthreads();
    if (threadIdx.x == 0)
        atomicAdd(loss, (wsum[0] + wsum[1] + wsum[2] + wsum[3]) * (1.0f / (float)n));
}

extern "C" void kernel_launch(void* const* d_in, const int* in_sizes, int n_in,
                              void* d_out, int out_size, void* d_ws, size_t ws_size,
                              hipStream_t stream) {
    const float* input  = (const float*)d_in[0];
    const float* target = (const float*)d_in[1];
    unsigned n = (unsigned)in_sizes[0];   // 16777216 = 2^24
    float* out  = (float*)d_out;
    float* loss = out + n;

    char* wsb = (char*)d_ws;
    size_t part_sz = (size_t)2 * HBLOCKS * NBINS * 4;       // 32 MB
    unsigned* partials = (unsigned*)(wsb);
    unsigned* H        = (unsigned*)(wsb + part_sz);        // 2*NBINS
    unsigned* Cin      = (unsigned*)(wsb + part_sz + 2 * NBINS * 4 + 256);
    unsigned* Ctg      = Cin + (NBINS + 1);
    float*    T        = (float*)(wsb + part_sz + 2 * NBINS * 4 + 2 * (NBINS + 64) * 4 + 512);
    char*     tails    = (char*)T + (size_t)n * 4;
    unsigned* ctrs     = (unsigned*)(tails);                // [in_lo, in_hi, tg_lo, tg_hi]
    float*    in_lo_v  = (float*)   (tails + 256);
    unsigned* in_lo_i  = (unsigned*)(tails + 256 + KIN * 4);
    float*    in_hi_v  = (float*)   (tails + 256 + KIN * 8);
    unsigned* in_hi_i  = (unsigned*)(tails + 256 + KIN * 12);
    float*    tg_lo    = (float*)   (tails + 256 + KIN * 16);
    float*    tg_hi    = (float*)   (tails + 256 + KIN * 16 + KTG * 4);

    (void)hipMemsetAsync(loss, 0, 4, stream);
    (void)hipMemsetAsync(ctrs, 0, 16, stream);

    unsigned n4 = n >> 2;
    unsigned gh = (n4 + 255) / 256;
    unsigned gn = (n + 255) / 256;

    hist_kernel<<<HBLOCKS, 256, 0, stream>>>(input,  partials, n4);
    hist_kernel<<<HBLOCKS, 256, 0, stream>>>(target, partials + (size_t)HBLOCKS * NBINS, n4);
    reduce_kernel<<<2 * NBINS / 256, 256, 0, stream>>>(partials, H);
    scan_kernel<<<2, 1024, 0, stream>>>(H, Cin);   // block 0 -> Cin, block 1 -> Cin+(NBINS+1)=Ctg

    buildT_kernel<<<(n4 + 255) / 256, 256, 0, stream>>>(Ctg, T, n);

    // tails: collect, then exact target order stats (overwrite T ends), then exact input match
    collect_kernel<<<gn, 256, 0, stream>>>(input, Cin, in_lo_v, in_lo_i, in_hi_v, in_hi_i,
                                           &ctrs[0], &ctrs[1], n, KIN, 1);
    collect_kernel<<<gn, 256, 0, stream>>>(target, Ctg, tg_lo, nullptr, tg_hi, nullptr,
                                           &ctrs[2], &ctrs[3], n, KTG, 0);
    exact_target_kernel<<<dim3((KTG + 1023) / 1024, 2), 1024, 0, stream>>>(tg_lo, tg_hi, ctrs, T, n);
    exact_input_kernel<<<dim3((KIN + 1023) / 1024, 2), 1024, 0, stream>>>(in_lo_v, in_lo_i, in_hi_v, in_hi_i,
                                                                          ctrs, T, out, loss, n);

    match_loss_kernel<<<gh, 256, 0, stream>>>(input, Cin, T, out, loss, n);
}

// Round 7
// 707.498 us; speedup vs baseline: 5.1214x; 1.2514x over previous
//
#include <hip/hip_runtime.h>
#include <cstdint>

// HistogramLoss via coarse empirical-CDF tables (LDS histograms) + per-input-bin linear
// map (AB table) + exact tail handling in small side arrays. No big T table.
// matched[i] = sorted(target)[count(input <= input[i]) - 1], loss = mean((matched-input)^2)

#define NBINS    8192u              // uniform bins over [-16, 16), 32 KB LDS histogram
#define BINSCALE 256.0              // NBINS / 32
#define HBLOCKS  512u               // histogram partial blocks
#define KIN      2048u              // input tail rank cutoff (per side)
#define KTG      4096u              // target tail rank cutoff (per side)

__device__ __forceinline__ void bin_and_frac(float x, unsigned& b, float& frac) {
    double d = ((double)x + 16.0) * BINSCALE;
    if (d < 0.0) d = 0.0;
    if (d >= (double)NBINS) d = (double)NBINS - 1e-7;
    b = (unsigned)d;
    frac = (float)(d - (double)b);
}

// LDS-private histogram; flush per-block partials with plain coalesced stores.
__global__ void hist_kernel(const float* __restrict__ x, unsigned* __restrict__ partials, unsigned n4) {
    __shared__ unsigned h[NBINS];
    for (unsigned i = threadIdx.x; i < NBINS; i += 256) h[i] = 0;
    __syncthreads();
    unsigned stride = gridDim.x * 256;
    for (unsigned i = blockIdx.x * 256 + threadIdx.x; i < n4; i += stride) {
        float4 v = ((const float4*)x)[i];
        unsigned b; float f;
        bin_and_frac(v.x, b, f); atomicAdd(&h[b], 1u);
        bin_and_frac(v.y, b, f); atomicAdd(&h[b], 1u);
        bin_and_frac(v.z, b, f); atomicAdd(&h[b], 1u);
        bin_and_frac(v.w, b, f); atomicAdd(&h[b], 1u);
    }
    __syncthreads();
    unsigned base = blockIdx.x * NBINS;
    for (unsigned i = threadIdx.x; i < NBINS; i += 256) partials[base + i] = h[i];
}

// Column-sum of HBLOCKS x NBINS partial matrices (2 histograms back to back).
__global__ void reduce_kernel(const unsigned* __restrict__ partials, unsigned* __restrict__ H) {
    unsigned col = blockIdx.x * 256 + threadIdx.x;           // [0, 2*NBINS)
    unsigned hist = col / NBINS, c = col & (NBINS - 1);
    const unsigned* p = partials + (size_t)hist * HBLOCKS * NBINS + c;
    unsigned s0 = 0, s1 = 0, s2 = 0, s3 = 0;
    for (unsigned k = 0; k < HBLOCKS; k += 4) {
        s0 += p[(size_t)k * NBINS];
        s1 += p[(size_t)(k + 1) * NBINS];
        s2 += p[(size_t)(k + 2) * NBINS];
        s3 += p[(size_t)(k + 3) * NBINS];
    }
    H[col] = s0 + s1 + s2 + s3;
}

// Exclusive scan of one 8192-bin histogram per block -> C[NBINS+1]. grid = 2 blocks.
__global__ void scan_kernel(const unsigned* __restrict__ H, unsigned* __restrict__ C) {
    __shared__ unsigned s[1024];
    const unsigned* h = H + blockIdx.x * NBINS;
    unsigned* c = C + blockIdx.x * (NBINS + 1);
    unsigned base = threadIdx.x * 8;
    unsigned v[8]; unsigned own = 0;
    #pragma unroll
    for (int k = 0; k < 8; k++) { v[k] = h[base + k]; own += v[k]; }
    s[threadIdx.x] = own; __syncthreads();
    for (unsigned off = 1; off < 1024; off <<= 1) {
        unsigned t = (threadIdx.x >= off) ? s[threadIdx.x - off] : 0u;
        __syncthreads();
        s[threadIdx.x] += t;
        __syncthreads();
    }
    unsigned ex = s[threadIdx.x] - own;
    #pragma unroll
    for (int k = 0; k < 8; k++) { unsigned t = v[k]; c[base + k] = ex; ex += t; }
    if (threadIdx.x == 1023) c[NBINS] = s[1023];
}

// Per-input-bin linear map: matched(frac) = A[b] + B[b]*frac (chord of target invCDF over
// the bin's rank range). Also computes tail boundary bins blo/bhi via atomics.
__global__ void buildAB_kernel(const unsigned* __restrict__ Cin, const unsigned* __restrict__ Ctg,
                               float2* __restrict__ AB, int* __restrict__ hdr, unsigned n) {
    unsigned b = blockIdx.x * blockDim.x + threadIdx.x;
    if (b >= NBINS) return;
    unsigned r0 = Cin[b], r1 = Cin[b + 1];
    if (r1 <= KIN) atomicMax(&hdr[0], (int)b);                 // blo
    if (r0 >= n - KIN) atomicMin(&hdr[1], (int)b);             // bhi
    if (r1 == r0) { AB[b] = make_float2(0.f, 0.f); return; }   // empty bin, never accessed
    const float w = 32.0f / (float)NBINS;
    float v[2];
    unsigned rr[2] = {r0, r1};
    #pragma unroll
    for (int k = 0; k < 2; k++) {
        unsigned r = rr[k]; if (r > n - 1) r = n - 1;
        unsigned lo = 0, hi = NBINS;                            // Ctg[lo] <= r < Ctg[hi]
        while (hi - lo > 1) { unsigned mid = (lo + hi) >> 1; if (Ctg[mid] <= r) lo = mid; else hi = mid; }
        unsigned c0 = Ctg[lo], c1 = Ctg[lo + 1];
        v[k] = -16.0f + (float)lo * w + w * ((float)(r - c0 + 1) / (float)(c1 - c0));
    }
    AB[b] = make_float2(v[0], v[1] - v[0]);
}

// Collect target tail elements (whole-bin criterion, rank-closed sets, counts <= KTG).
__global__ void collect_tg_kernel(const float* __restrict__ x, const unsigned* __restrict__ C,
                                  float* __restrict__ vlo, float* __restrict__ vhi,
                                  unsigned* __restrict__ ctr_lo, unsigned* __restrict__ ctr_hi,
                                  unsigned n) {
    unsigned i = blockIdx.x * blockDim.x + threadIdx.x;
    if (i >= n) return;
    float v = x[i];
    unsigned b; float f;
    bin_and_frac(v, b, f);
    unsigned c0 = C[b], c1 = C[b + 1];
    if (c1 <= KTG) {
        unsigned p = atomicAdd(ctr_lo, 1u);
        vlo[p] = v;
    } else if (c0 >= n - KTG) {
        unsigned p = atomicAdd(ctr_hi, 1u);
        vhi[p] = v;
    }
}

// Exact target order statistics into small arrays Tlo[r] (ranks [0,m)) and
// Thi[KTG-1-...] (top ranks). grid (4, 2): blockIdx.y = side, one j per thread.
__global__ void exact_target_kernel(const float* __restrict__ tg_lo, const float* __restrict__ tg_hi,
                                    const unsigned* __restrict__ ctrs,
                                    float* __restrict__ Tlo, float* __restrict__ Thi) {
    __shared__ __align__(16) float v[KTG];
    int side = blockIdx.y;
    const float* src = side ? tg_hi : tg_lo;
    unsigned m = ctrs[side ? 3 : 2];
    if (m > KTG) m = KTG;
    float sgn = side ? -1.f : 1.f;
    for (unsigned k = threadIdx.x; k < m; k += 1024) v[k] = sgn * src[k];
    __syncthreads();
    unsigned j = blockIdx.x * 1024 + threadIdx.x;
    if (j >= m) return;
    float y = v[j];
    unsigned lt = 0, le = 0;
    unsigned m4 = m & ~3u;
    for (unsigned k = 0; k < m4; k += 4) {
        float4 z = *(const float4*)&v[k];
        lt += (z.x < y) + (z.y < y) + (z.z < y) + (z.w < y);
        le += (z.x <= y) + (z.y <= y) + (z.z <= y) + (z.w <= y);
    }
    for (unsigned k = m4; k < m; k++) { lt += (v[k] < y); le += (v[k] <= y); }
    float yo = sgn * y;
    if (side) {
        for (unsigned idx = KTG - le; idx < KTG - lt; idx++) Thi[idx] = yo;  // global rank n-KTG+idx
    } else {
        for (unsigned r = lt; r < le; r++) Tlo[r] = yo;
    }
}

// Main fused pass: interp-match + loss for mid elements; collect input tail elements.
__global__ void match_loss_kernel(const float* __restrict__ input,
                                  const float2* __restrict__ AB, const int* __restrict__ hdr,
                                  float* __restrict__ vlo, unsigned* __restrict__ ilo,
                                  float* __restrict__ vhi, unsigned* __restrict__ ihi,
                                  unsigned* __restrict__ ctrs,
                                  float* __restrict__ out, float* __restrict__ loss,
                                  unsigned n) {
    int blo = hdr[0], bhi = hdr[1];
    unsigned i = blockIdx.x * blockDim.x + threadIdx.x;
    unsigned n4 = n >> 2;
    float acc = 0.f;
    if (i < n4) {
        float4 vv = ((const float4*)input)[i];
        float xs[4] = {vv.x, vv.y, vv.z, vv.w};
        float m[4]; bool tail[4]; bool anytail = false;
        #pragma unroll
        for (int k = 0; k < 4; k++) {
            float x = xs[k];
            unsigned b; float frac;
            bin_and_frac(x, b, frac);
            if ((int)b <= blo) {
                tail[k] = true; anytail = true; m[k] = 0.f;
                unsigned p = atomicAdd(&ctrs[0], 1u);
                vlo[p] = x; ilo[p] = 4 * i + k;
                continue;
            }
            if ((int)b >= bhi) {
                tail[k] = true; anytail = true; m[k] = 0.f;
                unsigned p = atomicAdd(&ctrs[1], 1u);
                vhi[p] = x; ihi[p] = 4 * i + k;
                continue;
            }
            tail[k] = false;
            float2 ab = AB[b];
            float mv = ab.x + ab.y * frac;
            m[k] = mv;
            float d = mv - x;
            acc += d * d;
        }
        if (!anytail) {
            ((float4*)out)[i] = make_float4(m[0], m[1], m[2], m[3]);
        } else {
            #pragma unroll
            for (int k = 0; k < 4; k++)
                if (!tail[k]) out[4 * i + k] = m[k];
        }
    }
    #pragma unroll
    for (int off = 32; off > 0; off >>= 1) acc += __shfl_down(acc, off, 64);
    __shared__ float wsum[4];
    int wv = threadIdx.x >> 6;
    if ((threadIdx.x & 63) == 0) wsum[wv] = acc;
    __syncthreads();
    if (threadIdx.x == 0)
        atomicAdd(loss, (wsum[0] + wsum[1] + wsum[2] + wsum[3]) * (1.0f / (float)n));
}

// Exact input tail matching. grid (2, 2): blockIdx.y = side, one j per thread.
__global__ void exact_input_kernel(const float* __restrict__ in_lo_v, const unsigned* __restrict__ in_lo_i,
                                   const float* __restrict__ in_hi_v, const unsigned* __restrict__ in_hi_i,
                                   const unsigned* __restrict__ ctrs,
                                   const float* __restrict__ Tlo, const float* __restrict__ Thi,
                                   float* __restrict__ out, float* __restrict__ loss, unsigned n) {
    __shared__ __align__(16) float v[KIN];
    int side = blockIdx.y;
    const float* sv = side ? in_hi_v : in_lo_v;
    const unsigned* si = side ? in_hi_i : in_lo_i;
    unsigned m = ctrs[side ? 1 : 0];
    if (m > KIN) m = KIN;
    float sgn = side ? -1.f : 1.f;
    for (unsigned k = threadIdx.x; k < m; k += 1024) v[k] = sgn * sv[k];
    __syncthreads();
    unsigned j = blockIdx.x * 1024 + threadIdx.x;
    float d2 = 0.f;
    if (j < m) {
        float y = v[j];
        unsigned lt = 0, le = 0;
        unsigned m4 = m & ~3u;
        for (unsigned k = 0; k < m4; k += 4) {
            float4 z = *(const float4*)&v[k];
            lt += (z.x < y) + (z.y < y) + (z.z < y) + (z.w < y);
            le += (z.x <= y) + (z.y <= y) + (z.z <= y) + (z.w <= y);
        }
        for (unsigned k = m4; k < m; k++) { lt += (v[k] < y); le += (v[k] <= y); }
        // bottom: global rank = le-1 (< KIN <= KTG). top: global rank = n-1-lt -> Thi[KTG-1-lt].
        float mv = side ? Thi[KTG - 1 - lt] : Tlo[le - 1];
        float x = sgn * y;
        out[si[j]] = mv;
        float d = mv - x;
        d2 = d * d;
    }
    #pragma unroll
    for (int off = 32; off > 0; off >>= 1) d2 += __shfl_down(d2, off, 64);
    if ((threadIdx.x & 63) == 0 && d2 != 0.f)
        atomicAdd(loss, d2 * (1.0f / (float)n));
}

extern "C" void kernel_launch(void* const* d_in, const int* in_sizes, int n_in,
                              void* d_out, int out_size, void* d_ws, size_t ws_size,
                              hipStream_t stream) {
    const float* input  = (const float*)d_in[0];
    const float* target = (const float*)d_in[1];
    unsigned n = (unsigned)in_sizes[0];   // 16777216 = 2^24
    float* out  = (float*)d_out;
    float* loss = out + n;

    char* wsb = (char*)d_ws;
    size_t part_sz = (size_t)2 * HBLOCKS * NBINS * 4;       // 32 MB
    unsigned* partials = (unsigned*)(wsb);
    unsigned* H        = (unsigned*)(wsb + part_sz);        // 2*NBINS
    unsigned* Cin      = (unsigned*)(wsb + part_sz + 2 * NBINS * 4 + 256);
    unsigned* Ctg      = Cin + (NBINS + 1);
    char*     aux      = wsb + part_sz + 2 * NBINS * 4 + 2 * (NBINS + 64) * 4 + 512;
    float2*   AB       = (float2*)  (aux);                  // 64 KB
    int*      hdr      = (int*)     (aux + NBINS * 8);      // [blo, bhi]
    unsigned* ctrs     = (unsigned*)(aux + NBINS * 8 + 64); // [in_lo, in_hi, tg_lo, tg_hi]
    char*     tails    = aux + NBINS * 8 + 256;
    float*    in_lo_v  = (float*)   (tails);
    unsigned* in_lo_i  = (unsigned*)(tails + KIN * 4);
    float*    in_hi_v  = (float*)   (tails + KIN * 8);
    unsigned* in_hi_i  = (unsigned*)(tails + KIN * 12);
    float*    tg_lo    = (float*)   (tails + KIN * 16);
    float*    tg_hi    = (float*)   (tails + KIN * 16 + KTG * 4);
    float*    Tlo      = (float*)   (tails + KIN * 16 + KTG * 8);
    float*    Thi      = (float*)   (tails + KIN * 16 + KTG * 12);

    (void)hipMemsetAsync(loss, 0, 4, stream);
    (void)hipMemsetAsync(ctrs, 0, 16, stream);
    (void)hipMemsetAsync(&hdr[0], 0, 4, stream);            // blo = 0 (bin 0 always tail-eligible)
    (void)hipMemsetAsync(&hdr[1], 0x7F, 4, stream);         // bhi = large

    unsigned n4 = n >> 2;
    unsigned gh = (n4 + 255) / 256;
    unsigned gn = (n + 255) / 256;

    hist_kernel<<<HBLOCKS, 256, 0, stream>>>(input,  partials, n4);
    hist_kernel<<<HBLOCKS, 256, 0, stream>>>(target, partials + (size_t)HBLOCKS * NBINS, n4);
    reduce_kernel<<<2 * NBINS / 256, 256, 0, stream>>>(partials, H);
    scan_kernel<<<2, 1024, 0, stream>>>(H, Cin);   // block 0 -> Cin, block 1 -> Ctg

    buildAB_kernel<<<NBINS / 256, 256, 0, stream>>>(Cin, Ctg, AB, hdr, n);

    collect_tg_kernel<<<gn, 256, 0, stream>>>(target, Ctg, tg_lo, tg_hi, &ctrs[2], &ctrs[3], n);
    exact_target_kernel<<<dim3((KTG + 1023) / 1024, 2), 1024, 0, stream>>>(tg_lo, tg_hi, ctrs, Tlo, Thi);

    match_loss_kernel<<<gh, 256, 0, stream>>>(input, AB, hdr, in_lo_v, in_lo_i, in_hi_v, in_hi_i,
                                              ctrs, out, loss, n);
    exact_input_kernel<<<dim3((KIN + 1023) / 1024, 2), 1024, 0, stream>>>(in_lo_v, in_lo_i, in_hi_v, in_hi_i,
                                                                          ctrs, Tlo, Thi, out, loss, n);
}